// Round 10
// baseline (185.535 us; speedup 1.0000x reference)
//
#include <hip/hip_runtime.h>
#include <stdint.h>

#define HW 262144            // 512*512
#define ACQ_N 2097152        // 8*1*512*512

// hw-native transcendentals (1 instr each)
#define LOG2F(x) __builtin_amdgcn_logf(x)
#define EXP2F(x) __builtin_amdgcn_exp2f(x)
#define SQRTF(x) __builtin_amdgcn_sqrtf(x)
#define RCPF(x)  __builtin_amdgcn_rcpf(x)

#define ROTL(x, r) __builtin_amdgcn_alignbit((x), (x), (32 - (r)) & 31)

// ---------- host-side threefry2x32 for key derivation ----------
static inline void tf2x32_host(uint32_t k0, uint32_t k1, uint32_t c0, uint32_t c1,
                               uint32_t& o0, uint32_t& o1) {
  const uint32_t ks2 = k0 ^ k1 ^ 0x1BD11BDAu;
  uint32_t x0 = c0 + k0, x1 = c1 + k1;
#define TFR(r) { x0 += x1; x1 = (x1 << (r)) | (x1 >> (32 - (r))); x1 ^= x0; }
  TFR(13) TFR(15) TFR(26) TFR(6)
  x0 += k1;  x1 += ks2 + 1u;
  TFR(17) TFR(29) TFR(16) TFR(24)
  x0 += ks2; x1 += k0 + 2u;
  TFR(13) TFR(15) TFR(26) TFR(6)
  x0 += k0;  x1 += k1 + 3u;
  TFR(17) TFR(29) TFR(16) TFR(24)
  x0 += k1;  x1 += ks2 + 4u;
  TFR(13) TFR(15) TFR(26) TFR(6)
  x0 += ks2; x1 += k0 + 5u;
#undef TFR
  o0 = x0; o1 = x1;
}

// device: partitionable random_bits(32) for counter (0, idx): o0^o1
__device__ __forceinline__ uint32_t rbits32(uint32_t k0, uint32_t k1, uint32_t idx) {
  const uint32_t ks2 = k0 ^ k1 ^ 0x1BD11BDAu;
  uint32_t x0 = k0, x1 = idx + k1;
#define TFR(r) { x0 += x1; x1 = ROTL(x1, r); x1 ^= x0; }
  TFR(13) TFR(15) TFR(26) TFR(6)
  x0 += k1;  x1 += ks2 + 1u;
  TFR(17) TFR(29) TFR(16) TFR(24)
  x0 += ks2; x1 += k0 + 2u;
  TFR(13) TFR(15) TFR(26) TFR(6)
  x0 += k0;  x1 += k1 + 3u;
  TFR(17) TFR(29) TFR(16) TFR(24)
  x0 += k1;  x1 += ks2 + 4u;
  TFR(13) TFR(15) TFR(26) TFR(6)
  x0 += ks2; x1 += k0 + 5u;
#undef TFR
  return x0 ^ x1;
}

__device__ __forceinline__ float unit_from_bits(uint32_t b) {
  return __uint_as_float((b >> 9) | 0x3F800000u) - 1.0f;
}

// z = sqrt(2)*erfinv(x), Giles poly pre-scaled by sqrt(2); far branch real-branched.
__device__ __forceinline__ float sqrt2_erfinv(float x) {
  float ome = fmaf(-x, x, 1.0f);
  float w = -0.69314718056f * LOG2F(ome);
  float wn = w - 2.5f;
  float p = 3.974065e-08f;
  p = fmaf(p, wn, 4.854641e-07f);
  p = fmaf(p, wn, -4.982823e-06f);
  p = fmaf(p, wn, -6.210531e-06f);
  p = fmaf(p, wn, 3.091200e-04f);
  p = fmaf(p, wn, -1.773035e-03f);
  p = fmaf(p, wn, -5.908135e-03f);
  p = fmaf(p, wn, 3.488029e-01f);
  p = fmaf(p, wn, 2.123314e+00f);
  if (__builtin_expect(w >= 5.0f, 0)) {
    float wf = SQRTF(w) - 3.0f;
    float q = -2.831458e-04f;
    q = fmaf(q, wf, 1.427657e-04f);
    q = fmaf(q, wf, 1.908260e-03f);
    q = fmaf(q, wf, -5.195013e-03f);
    q = fmaf(q, wf, 8.116892e-03f);
    q = fmaf(q, wf, -1.0779791e-02f);
    q = fmaf(q, wf, 1.3348579e-02f);
    q = fmaf(q, wf, 1.416582e+00f);
    q = fmaf(q, wf, 4.006434e+00f);
    p = q;
  }
  return p * x;
}

// ---------- specialized frame loops (class-pure, branches hoisted) ----------
__device__ __forceinline__ float loop_fg(float base, float fw, float fa, float gw,
                                         uint32_t idx, int nf,
                                         uint32_t ku0, uint32_t ku1,
                                         uint32_t kn0, uint32_t kn1) {
  float nfa = -fa, fac = fa * 0.52876637294f;
  float acc = 0.0f;
#pragma unroll 2
  for (int f = 0; f < nf; ++f) {
    uint32_t ub = rbits32(ku0, ku1, idx);
    uint32_t nb = rbits32(kn0, kn1, idx);
    idx += (uint32_t)HW;
    float u = fminf(fmaxf(unit_from_bits(ub), 1e-6f), 0.999999f);
    float pw = EXP2F(fmaf(nfa, LOG2F(-LOG2F(u)), fac));
    float z = sqrt2_erfinv(fmaf(unit_from_bits(nb), 2.0f, -0.99999994f));
    float t = fmaf(gw, z, fmaf(fw, pw, base));
    acc += fminf(fmaxf(t, 0.0f), 1.0f);
  }
  return acc * RCPF((float)nf);
}

__device__ __forceinline__ float loop_f(float base, float fw, float fa,
                                        uint32_t idx, int nf,
                                        uint32_t ku0, uint32_t ku1) {
  float nfa = -fa, fac = fa * 0.52876637294f;
  float acc = 0.0f;
#pragma unroll 2
  for (int f = 0; f < nf; ++f) {
    uint32_t ub = rbits32(ku0, ku1, idx);
    idx += (uint32_t)HW;
    float u = fminf(fmaxf(unit_from_bits(ub), 1e-6f), 0.999999f);
    float pw = EXP2F(fmaf(nfa, LOG2F(-LOG2F(u)), fac));
    acc += fminf(fmaxf(fmaf(fw, pw, base), 0.0f), 1.0f);
  }
  return acc * RCPF((float)nf);
}

__device__ __forceinline__ float loop_g(float base, float gw,
                                        uint32_t idx, int nf,
                                        uint32_t kn0, uint32_t kn1) {
  float acc = 0.0f;
#pragma unroll 2
  for (int f = 0; f < nf; ++f) {
    uint32_t nb = rbits32(kn0, kn1, idx);
    idx += (uint32_t)HW;
    float z = sqrt2_erfinv(fmaf(unit_from_bits(nb), 2.0f, -0.99999994f));
    acc += fminf(fmaxf(fmaf(gw, z, base), 0.0f), 1.0f);
  }
  return acc * RCPF((float)nf);
}

// ================= compacted path (atomic-free) =================
// ws: float partial[512] @0 ; u32 blockcnt[512][4] @2048 ; u32 remarr[8][HW] @10240 ;
//     float4 packed[8][HW] @10240+8MB   (full tier only)

// phase 1: per-block class counts + per-block bias partial (no atomics)
__global__ __launch_bounds__(256) void count_cls(const float* __restrict__ inp,
                                                 uint32_t* __restrict__ blockcnt,
                                                 float* __restrict__ partial) {
  int blk = blockIdx.x;                 // 512 blocks: 8 batches x 64 chunks
  int b = blk >> 6, chunk = blk & 63;
  const float* pb = inp + (size_t)b * 5 * HW;
  int off = (chunk << 12) + threadIdx.x;
  int lane = threadIdx.x & 63, wid = threadIdx.x >> 6;

  int lc0 = 0, lc1 = 0, lc2 = 0, lc3 = 0;
  float s = 0.0f;
#pragma unroll
  for (int k = 0; k < 16; ++k) {
    int i = off + (k << 8);
    float f2 = pb[2 * HW + i];
    float f4 = pb[4 * HW + i];
    s += pb[HW + i];
    int cls = (f2 > 0.0f ? 1 : 0) | (f4 > 0.0f ? 2 : 0);
    lc0 += (cls == 0); lc1 += (cls == 1); lc2 += (cls == 2); lc3 += (cls == 3);
  }
  for (int o = 32; o; o >>= 1) {
    lc0 += __shfl_down(lc0, o); lc1 += __shfl_down(lc1, o);
    lc2 += __shfl_down(lc2, o); lc3 += __shfl_down(lc3, o);
    s   += __shfl_down(s, o);
  }
  __shared__ uint32_t scnt[4][4];
  __shared__ float sb[4];
  if (lane == 0) {
    scnt[wid][0] = lc0; scnt[wid][1] = lc1;
    scnt[wid][2] = lc2; scnt[wid][3] = lc3;
    sb[wid] = s;
  }
  __syncthreads();
  if (threadIdx.x < 4)
    blockcnt[blk * 4 + threadIdx.x] = scnt[0][threadIdx.x] + scnt[1][threadIdx.x]
                                    + scnt[2][threadIdx.x] + scnt[3][threadIdx.x];
  if (threadIdx.x == 0)
    partial[blk] = sb[0] + sb[1] + sb[2] + sb[3];
}

// phase 2 (full tier): inline scan + scatter of slot-ordered packed operands;
// also emits the center output (all reads coalesced).
__global__ __launch_bounds__(256) void scatter_pack(const float* __restrict__ inp,
                                                    const uint32_t* __restrict__ blockcnt,
                                                    const float* __restrict__ partial,
                                                    uint32_t* __restrict__ remarr,
                                                    float4* __restrict__ packed,
                                                    float* __restrict__ out) {
  int blk = blockIdx.x;                 // 512 blocks: 8 batches x 64 chunks
  int b = blk >> 6, chunk = blk & 63;
  int tid = threadIdx.x, wid = tid >> 6, lane = tid & 63;
  const float* pb = inp + (size_t)b * 5 * HW;

  __shared__ float s_bias;
  __shared__ uint32_t s_tot[4], s_pre[4], srun[4];
  // wave 0: finalize bias; waves 0-3: inline scan (wave wid = class wid)
  {
    uint32_t v = blockcnt[(((b << 6) | lane) << 2) | wid];
    uint32_t m = (lane < chunk) ? v : 0u;
    uint32_t tot = v, pre = m;
    for (int o = 32; o; o >>= 1) {
      tot += __shfl_down(tot, o);
      pre += __shfl_down(pre, o);
    }
    if (lane == 0) { s_tot[wid] = tot; s_pre[wid] = pre; }
  }
  if (tid < 64) {
    float s = partial[(b << 6) | tid];
    for (int o = 32; o; o >>= 1) s += __shfl_down(s, o);
    if (tid == 0) s_bias = fmaxf(s * (1.0f / 262144.0f), 0.0f);
  }
  __syncthreads();
  if (tid < 4) {
    uint32_t cb = 0;
    for (int cc = 0; cc < tid; ++cc) cb += s_tot[cc];
    srun[tid] = cb + s_pre[tid];
  }
  __syncthreads();
  float bias = s_bias;

  __shared__ uint32_t wcnt[4][4];
  uint32_t* rbase = remarr + (size_t)b * HW;
  float4*   kbase = packed + (size_t)b * HW;
  float*    outc  = out + ACQ_N + (size_t)b * HW;
  uint64_t below = (1ull << lane) - 1ull;

  for (int k = 0; k < 16; ++k) {
    int i = (chunk << 12) + (k << 8) + tid;
    float img = pb[i];
    float fw  = fmaxf(pb[2 * HW + i], 0.0f);
    float fa  = fmaxf(pb[3 * HW + i], 0.0f);
    float gw  = fmaxf(pb[4 * HW + i], 0.0f);
    float base = img + bias;
    // center = clip(base + fw*(1/(fa+1))^fa, 0, 1)  (coalesced write)
    float cpw = EXP2F(-fa * LOG2F(fa + 1.0f));
    outc[i] = fminf(fmaxf(fmaf(fw, cpw, base), 0.0f), 1.0f);

    int cls = (fw > 0.0f ? 1 : 0) | (gw > 0.0f ? 2 : 0);
    uint64_t ball[4];
#pragma unroll
    for (int c = 0; c < 4; ++c) ball[c] = __ballot(cls == c);
    int rank = __popcll(ball[cls] & below);
    if (lane == 0) {
#pragma unroll
      for (int c = 0; c < 4; ++c) wcnt[wid][c] = (uint32_t)__popcll(ball[c]);
    }
    __syncthreads();
    uint32_t mybase = srun[cls];
    for (int w = 0; w < wid; ++w) mybase += wcnt[w][cls];
    uint32_t slot = mybase + (uint32_t)rank;
    rbase[slot] = (uint32_t)i;
    kbase[slot] = make_float4(base, fw, fa, gw);   // same-class lanes: contiguous
    __syncthreads();
    if (tid < 4)
      srun[tid] += wcnt[0][tid] + wcnt[1][tid] + wcnt[2][tid] + wcnt[3][tid];
    __syncthreads();
  }
}

// phase 3 (full tier): coalesced packed reads, class-pure specialized loops
__global__ __launch_bounds__(256) void acquire_packed(
    const int* __restrict__ frames, const uint32_t* __restrict__ remarr,
    const float4* __restrict__ packed, float* __restrict__ out,
    uint32_t ku0, uint32_t ku1, uint32_t kn0, uint32_t kn1) {
  int b = blockIdx.x >> 10;
  int slot = ((blockIdx.x & 1023) << 8) | threadIdx.x;
  float4 op = packed[(size_t)b * HW + slot];   // coalesced 16 B
  uint32_t rem = remarr[(size_t)b * HW + slot];
  float base = op.x, fw = op.y, fa = op.z, gw = op.w;

  int nf = frames[b];                      // block-uniform
  bool fAny = __any(fw > 0.0f);            // wave-uniform
  bool gAny = __any(gw > 0.0f);
  uint32_t idx = ((uint32_t)b << 22) + rem;

  float res;
  if (fAny) {
    if (gAny) res = loop_fg(base, fw, fa, gw, idx, nf, ku0, ku1, kn0, kn1);
    else      res = loop_f(base, fw, fa, idx, nf, ku0, ku1);
  } else if (gAny) {
    res = loop_g(base, gw, idx, nf, kn0, kn1);
  } else {
    res = fminf(fmaxf(base, 0.0f), 1.0f);  // all frames identical
  }
  out[(size_t)b * HW + rem] = res;
}

// ================= mid tier (R8-style, scattered gather) =================
__global__ __launch_bounds__(256) void scatter_cls(const float* __restrict__ inp,
                                                   const uint32_t* __restrict__ blockcnt,
                                                   uint32_t* __restrict__ slotidx) {
  int blk = blockIdx.x;
  int b = blk >> 6, chunk = blk & 63;
  int tid = threadIdx.x, wid = tid >> 6, lane = tid & 63;
  const float* pb = inp + (size_t)b * 5 * HW;

  __shared__ uint32_t s_tot[4], s_pre[4], srun[4];
  {
    uint32_t v = blockcnt[(((b << 6) | lane) << 2) | wid];
    uint32_t m = (lane < chunk) ? v : 0u;
    uint32_t tot = v, pre = m;
    for (int o = 32; o; o >>= 1) {
      tot += __shfl_down(tot, o);
      pre += __shfl_down(pre, o);
    }
    if (lane == 0) { s_tot[wid] = tot; s_pre[wid] = pre; }
  }
  __syncthreads();
  if (tid < 4) {
    uint32_t cb = 0;
    for (int cc = 0; cc < tid; ++cc) cb += s_tot[cc];
    srun[tid] = cb + s_pre[tid];
  }
  __syncthreads();

  __shared__ uint32_t wcnt[4][4];
  uint32_t* sbase = slotidx + (size_t)b * HW;
  uint64_t below = (1ull << lane) - 1ull;
  for (int k = 0; k < 16; ++k) {
    int i = (chunk << 12) + (k << 8) + tid;
    float f2 = pb[2 * HW + i];
    float f4 = pb[4 * HW + i];
    int cls = (f2 > 0.0f ? 1 : 0) | (f4 > 0.0f ? 2 : 0);
    uint64_t ball[4];
#pragma unroll
    for (int c = 0; c < 4; ++c) ball[c] = __ballot(cls == c);
    int rank = __popcll(ball[cls] & below);
    if (lane == 0) {
#pragma unroll
      for (int c = 0; c < 4; ++c) wcnt[wid][c] = (uint32_t)__popcll(ball[c]);
    }
    __syncthreads();
    uint32_t mybase = srun[cls];
    for (int w = 0; w < wid; ++w) mybase += wcnt[w][cls];
    sbase[mybase + (uint32_t)rank] = (uint32_t)i;
    __syncthreads();
    if (tid < 4)
      srun[tid] += wcnt[0][tid] + wcnt[1][tid] + wcnt[2][tid] + wcnt[3][tid];
    __syncthreads();
  }
}

__global__ __launch_bounds__(256) void acquire_cls(
    const float* __restrict__ inp, const int* __restrict__ frames,
    const float* __restrict__ partial, const uint32_t* __restrict__ slotidx,
    float* __restrict__ out,
    uint32_t ku0, uint32_t ku1, uint32_t kn0, uint32_t kn1) {
  int b = blockIdx.x >> 10;
  int slot = ((blockIdx.x & 1023) << 8) | threadIdx.x;
  uint32_t rem = slotidx[(size_t)b * HW + slot];

  __shared__ float s_bias;
  if (threadIdx.x < 64) {
    float s = partial[(b << 6) | threadIdx.x];
    for (int off = 32; off; off >>= 1) s += __shfl_down(s, off);
    if (threadIdx.x == 0) s_bias = fmaxf(s * (1.0f / 262144.0f), 0.0f);
  }
  const float* pb = inp + (size_t)b * 5 * HW;
  float img = pb[rem];
  float fw  = fmaxf(pb[2 * HW + rem], 0.0f);
  float fa  = fmaxf(pb[3 * HW + rem], 0.0f);
  float gw  = fmaxf(pb[4 * HW + rem], 0.0f);
  __syncthreads();
  float base = img + s_bias;

  int nf = frames[b];
  bool fAny = __any(fw > 0.0f);
  bool gAny = __any(gw > 0.0f);
  uint32_t idx = ((uint32_t)b << 22) + rem;

  float res;
  if (fAny) {
    if (gAny) res = loop_fg(base, fw, fa, gw, idx, nf, ku0, ku1, kn0, kn1);
    else      res = loop_f(base, fw, fa, idx, nf, ku0, ku1);
  } else if (gAny) {
    res = loop_g(base, gw, idx, nf, kn0, kn1);
  } else {
    res = fminf(fmaxf(base, 0.0f), 1.0f);
  }
  out[(size_t)b * HW + rem] = res;
  float cpw = EXP2F(-fa * LOG2F(fa + 1.0f));
  out[ACQ_N + (size_t)b * HW + rem] = fminf(fmaxf(fmaf(fw, cpw, base), 0.0f), 1.0f);
}

// ================= plain tier (R5, proven) =================
__global__ __launch_bounds__(256) void bias_partial(const float* __restrict__ inp,
                                                    float* __restrict__ partial) {
  int blk = blockIdx.x;
  int b = blk >> 6, chunk = blk & 63;
  const float4* src = (const float4*)(inp + ((size_t)b * 5 + 1) * HW
                                          + (size_t)chunk * 4096);
  int t = threadIdx.x;
  float s = 0.0f;
#pragma unroll
  for (int k = 0; k < 4; ++k) {
    float4 v = src[t + k * 256];
    s += (v.x + v.y) + (v.z + v.w);
  }
  for (int off = 32; off; off >>= 1) s += __shfl_down(s, off);
  __shared__ float ws4[4];
  if ((t & 63) == 0) ws4[t >> 6] = s;
  __syncthreads();
  if (t == 0) partial[blk] = ws4[0] + ws4[1] + ws4[2] + ws4[3];
}

__global__ __launch_bounds__(256) void acquire_plain(
    const float* __restrict__ inp, const int* __restrict__ frames,
    const float* __restrict__ partial, float* __restrict__ out,
    uint32_t ku0, uint32_t ku1, uint32_t kn0, uint32_t kn1) {
  int b = blockIdx.x >> 10;
  int rem = ((blockIdx.x & 1023) << 8) | threadIdx.x;
  __shared__ float s_bias;
  if (threadIdx.x < 64) {
    float s = partial[(b << 6) | threadIdx.x];
    for (int off = 32; off; off >>= 1) s += __shfl_down(s, off);
    if (threadIdx.x == 0) s_bias = fmaxf(s * (1.0f / 262144.0f), 0.0f);
  }
  const float* pb = inp + (size_t)b * 5 * HW;
  float img = pb[rem];
  float fw  = fmaxf(pb[2 * HW + rem], 0.0f);
  float fa  = fmaxf(pb[3 * HW + rem], 0.0f);
  float gw  = fmaxf(pb[4 * HW + rem], 0.0f);
  __syncthreads();
  float base = img + s_bias;
  int nf = frames[b];
  uint32_t idx = ((uint32_t)b << 22) + (uint32_t)rem;
  float res = loop_fg(base, fw, fa, gw, idx, nf, ku0, ku1, kn0, kn1);
  out[(size_t)b * HW + rem] = res;
  float cpw = EXP2F(-fa * LOG2F(fa + 1.0f));
  out[ACQ_N + (size_t)b * HW + rem] = fminf(fmaxf(fmaf(fw, cpw, base), 0.0f), 1.0f);
}

extern "C" void kernel_launch(void* const* d_in, const int* in_sizes, int n_in,
                              void* d_out, int out_size, void* d_ws, size_t ws_size,
                              hipStream_t stream) {
  const float* inp    = (const float*)d_in[0];
  const int*   frames = (const int*)d_in[1];
  float* out = (float*)d_out;

  // jax_threefry_partitionable=True: split(key(42)) foldlike:
  // ku = cipher((0,42),(0,0)), kn = cipher((0,42),(0,1))
  uint32_t ku0, ku1, kn0, kn1;
  tf2x32_host(0u, 42u, 0u, 0u, ku0, ku1);
  tf2x32_host(0u, 42u, 0u, 1u, kn0, kn1);

  float*    partial  = (float*)d_ws;                     // 512 f32
  uint32_t* blockcnt = (uint32_t*)((char*)d_ws + 2048);  // 512*4 u32
  const size_t need_full = 10240 + (size_t)8 * HW * 4 + (size_t)8 * HW * 16;
  const size_t need_mid  = 10240 + (size_t)8 * HW * 4;

  if (ws_size >= need_full) {
    uint32_t* remarr = (uint32_t*)((char*)d_ws + 10240);
    float4*   packed = (float4*)((char*)d_ws + 10240 + (size_t)8 * HW * 4);
    count_cls<<<dim3(512), dim3(256), 0, stream>>>(inp, blockcnt, partial);
    scatter_pack<<<dim3(512), dim3(256), 0, stream>>>(inp, blockcnt, partial,
                                                      remarr, packed, out);
    acquire_packed<<<dim3(8192), dim3(256), 0, stream>>>(frames, remarr, packed,
                                                         out, ku0, ku1, kn0, kn1);
  } else if (ws_size >= need_mid) {
    uint32_t* slotidx = (uint32_t*)((char*)d_ws + 10240);
    count_cls<<<dim3(512), dim3(256), 0, stream>>>(inp, blockcnt, partial);
    scatter_cls<<<dim3(512), dim3(256), 0, stream>>>(inp, blockcnt, slotidx);
    acquire_cls<<<dim3(8192), dim3(256), 0, stream>>>(inp, frames, partial,
                                                      slotidx, out,
                                                      ku0, ku1, kn0, kn1);
  } else {
    bias_partial<<<dim3(512), dim3(256), 0, stream>>>(inp, partial);
    acquire_plain<<<dim3(8192), dim3(256), 0, stream>>>(inp, frames, partial, out,
                                                        ku0, ku1, kn0, kn1);
  }
}

// Round 11
// 165.382 us; speedup vs baseline: 1.1219x; 1.1219x over previous
//
#include <hip/hip_runtime.h>
#include <stdint.h>

#define HW 262144            // 512*512
#define ACQ_N 2097152        // 8*1*512*512

// hw-native transcendentals (1 instr each)
#define LOG2F(x) __builtin_amdgcn_logf(x)
#define EXP2F(x) __builtin_amdgcn_exp2f(x)
#define SQRTF(x) __builtin_amdgcn_sqrtf(x)
#define RCPF(x)  __builtin_amdgcn_rcpf(x)

#define ROTL(x, r) __builtin_amdgcn_alignbit((x), (x), (32 - (r)) & 31)

// ---------- host-side threefry2x32 for key derivation ----------
static inline void tf2x32_host(uint32_t k0, uint32_t k1, uint32_t c0, uint32_t c1,
                               uint32_t& o0, uint32_t& o1) {
  const uint32_t ks2 = k0 ^ k1 ^ 0x1BD11BDAu;
  uint32_t x0 = c0 + k0, x1 = c1 + k1;
#define TFR(r) { x0 += x1; x1 = (x1 << (r)) | (x1 >> (32 - (r))); x1 ^= x0; }
  TFR(13) TFR(15) TFR(26) TFR(6)
  x0 += k1;  x1 += ks2 + 1u;
  TFR(17) TFR(29) TFR(16) TFR(24)
  x0 += ks2; x1 += k0 + 2u;
  TFR(13) TFR(15) TFR(26) TFR(6)
  x0 += k0;  x1 += k1 + 3u;
  TFR(17) TFR(29) TFR(16) TFR(24)
  x0 += k1;  x1 += ks2 + 4u;
  TFR(13) TFR(15) TFR(26) TFR(6)
  x0 += ks2; x1 += k0 + 5u;
#undef TFR
  o0 = x0; o1 = x1;
}

// device: partitionable random_bits(32) for counter (0, idx): o0^o1
__device__ __forceinline__ uint32_t rbits32(uint32_t k0, uint32_t k1, uint32_t idx) {
  const uint32_t ks2 = k0 ^ k1 ^ 0x1BD11BDAu;
  uint32_t x0 = k0, x1 = idx + k1;
#define TFR(r) { x0 += x1; x1 = ROTL(x1, r); x1 ^= x0; }
  TFR(13) TFR(15) TFR(26) TFR(6)
  x0 += k1;  x1 += ks2 + 1u;
  TFR(17) TFR(29) TFR(16) TFR(24)
  x0 += ks2; x1 += k0 + 2u;
  TFR(13) TFR(15) TFR(26) TFR(6)
  x0 += k0;  x1 += k1 + 3u;
  TFR(17) TFR(29) TFR(16) TFR(24)
  x0 += k1;  x1 += ks2 + 4u;
  TFR(13) TFR(15) TFR(26) TFR(6)
  x0 += ks2; x1 += k0 + 5u;
#undef TFR
  return x0 ^ x1;
}

__device__ __forceinline__ float unit_from_bits(uint32_t b) {
  return __uint_as_float((b >> 9) | 0x3F800000u) - 1.0f;
}

// z = sqrt(2)*erfinv(x), Giles poly pre-scaled by sqrt(2); far branch real-branched.
__device__ __forceinline__ float sqrt2_erfinv(float x) {
  float ome = fmaf(-x, x, 1.0f);
  float w = -0.69314718056f * LOG2F(ome);
  float wn = w - 2.5f;
  float p = 3.974065e-08f;
  p = fmaf(p, wn, 4.854641e-07f);
  p = fmaf(p, wn, -4.982823e-06f);
  p = fmaf(p, wn, -6.210531e-06f);
  p = fmaf(p, wn, 3.091200e-04f);
  p = fmaf(p, wn, -1.773035e-03f);
  p = fmaf(p, wn, -5.908135e-03f);
  p = fmaf(p, wn, 3.488029e-01f);
  p = fmaf(p, wn, 2.123314e+00f);
  if (__builtin_expect(w >= 5.0f, 0)) {
    float wf = SQRTF(w) - 3.0f;
    float q = -2.831458e-04f;
    q = fmaf(q, wf, 1.427657e-04f);
    q = fmaf(q, wf, 1.908260e-03f);
    q = fmaf(q, wf, -5.195013e-03f);
    q = fmaf(q, wf, 8.116892e-03f);
    q = fmaf(q, wf, -1.0779791e-02f);
    q = fmaf(q, wf, 1.3348579e-02f);
    q = fmaf(q, wf, 1.416582e+00f);
    q = fmaf(q, wf, 4.006434e+00f);
    p = q;
  }
  return p * x;
}

// ---------- specialized frame loops (class-pure, branches hoisted) ----------
__device__ __forceinline__ float loop_fg(float base, float fw, float fa, float gw,
                                         uint32_t idx, int nf,
                                         uint32_t ku0, uint32_t ku1,
                                         uint32_t kn0, uint32_t kn1) {
  float nfa = -fa, fac = fa * 0.52876637294f;
  float acc = 0.0f;
#pragma unroll 2
  for (int f = 0; f < nf; ++f) {
    uint32_t ub = rbits32(ku0, ku1, idx);
    uint32_t nb = rbits32(kn0, kn1, idx);
    idx += (uint32_t)HW;
    float u = fminf(fmaxf(unit_from_bits(ub), 1e-6f), 0.999999f);
    float pw = EXP2F(fmaf(nfa, LOG2F(-LOG2F(u)), fac));
    float z = sqrt2_erfinv(fmaf(unit_from_bits(nb), 2.0f, -0.99999994f));
    float t = fmaf(gw, z, fmaf(fw, pw, base));
    acc += fminf(fmaxf(t, 0.0f), 1.0f);
  }
  return acc * RCPF((float)nf);
}

__device__ __forceinline__ float loop_f(float base, float fw, float fa,
                                        uint32_t idx, int nf,
                                        uint32_t ku0, uint32_t ku1) {
  float nfa = -fa, fac = fa * 0.52876637294f;
  float acc = 0.0f;
#pragma unroll 2
  for (int f = 0; f < nf; ++f) {
    uint32_t ub = rbits32(ku0, ku1, idx);
    idx += (uint32_t)HW;
    float u = fminf(fmaxf(unit_from_bits(ub), 1e-6f), 0.999999f);
    float pw = EXP2F(fmaf(nfa, LOG2F(-LOG2F(u)), fac));
    acc += fminf(fmaxf(fmaf(fw, pw, base), 0.0f), 1.0f);
  }
  return acc * RCPF((float)nf);
}

__device__ __forceinline__ float loop_g(float base, float gw,
                                        uint32_t idx, int nf,
                                        uint32_t kn0, uint32_t kn1) {
  float acc = 0.0f;
#pragma unroll 2
  for (int f = 0; f < nf; ++f) {
    uint32_t nb = rbits32(kn0, kn1, idx);
    idx += (uint32_t)HW;
    float z = sqrt2_erfinv(fmaf(unit_from_bits(nb), 2.0f, -0.99999994f));
    acc += fminf(fmaxf(fmaf(gw, z, base), 0.0f), 1.0f);
  }
  return acc * RCPF((float)nf);
}

// ================= compacted path (atomic-free, 1-barrier scatter) =============
// ws: float partial[512] @0 ; u32 blockcnt[512][4] @2048 ; u32 remarr[8][HW] @10240 ;
//     float4 packed[8][HW] @10240+8MB

// phase 1: per-block class counts + per-block bias partial (no atomics)
__global__ __launch_bounds__(256) void count_cls(const float* __restrict__ inp,
                                                 uint32_t* __restrict__ blockcnt,
                                                 float* __restrict__ partial) {
  int blk = blockIdx.x;                 // 512 blocks: 8 batches x 64 chunks
  int b = blk >> 6, chunk = blk & 63;
  const float* pb = inp + (size_t)b * 5 * HW;
  int off = (chunk << 12) + threadIdx.x;
  int lane = threadIdx.x & 63, wid = threadIdx.x >> 6;

  int lc0 = 0, lc1 = 0, lc2 = 0, lc3 = 0;
  float s = 0.0f;
#pragma unroll
  for (int k = 0; k < 16; ++k) {
    int i = off + (k << 8);
    float f2 = pb[2 * HW + i];
    float f4 = pb[4 * HW + i];
    s += pb[HW + i];
    int cls = (f2 > 0.0f ? 1 : 0) | (f4 > 0.0f ? 2 : 0);
    lc0 += (cls == 0); lc1 += (cls == 1); lc2 += (cls == 2); lc3 += (cls == 3);
  }
  for (int o = 32; o; o >>= 1) {
    lc0 += __shfl_down(lc0, o); lc1 += __shfl_down(lc1, o);
    lc2 += __shfl_down(lc2, o); lc3 += __shfl_down(lc3, o);
    s   += __shfl_down(s, o);
  }
  __shared__ uint32_t scnt[4][4];
  __shared__ float sb[4];
  if (lane == 0) {
    scnt[wid][0] = lc0; scnt[wid][1] = lc1;
    scnt[wid][2] = lc2; scnt[wid][3] = lc3;
    sb[wid] = s;
  }
  __syncthreads();
  if (threadIdx.x < 4)
    blockcnt[blk * 4 + threadIdx.x] = scnt[0][threadIdx.x] + scnt[1][threadIdx.x]
                                    + scnt[2][threadIdx.x] + scnt[3][threadIdx.x];
  if (threadIdx.x == 0)
    partial[blk] = sb[0] + sb[1] + sb[2] + sb[3];
}

// phase 2: single-barrier scan + scatter of slot-ordered packed operands;
// also emits the center output. Per-wave class offsets live in registers
// (wave-uniform via ballot/popcount) -> no barriers/LDS in the 16-iter loop.
__global__ __launch_bounds__(256) void scatter_pack(const float* __restrict__ inp,
                                                    const uint32_t* __restrict__ blockcnt,
                                                    const float* __restrict__ partial,
                                                    uint32_t* __restrict__ remarr,
                                                    float4* __restrict__ packed,
                                                    float* __restrict__ out) {
  int blk = blockIdx.x;                 // 512 blocks: 8 batches x 64 chunks
  int b = blk >> 6, chunk = blk & 63;
  int tid = threadIdx.x, wid = tid >> 6, lane = tid & 63;
  const float* pb = inp + (size_t)b * 5 * HW;
  uint64_t below = (1ull << lane) - 1ull;

  __shared__ float s_bias;
  __shared__ uint32_t s_tot[4], s_pre[4];
  __shared__ uint32_t swcnt[4][4];

  // batch-level scan: wave `wid` handles class `wid`; lane = chunk index
  {
    uint32_t v = blockcnt[(((b << 6) | lane) << 2) | wid];
    uint32_t m = (lane < chunk) ? v : 0u;
    uint32_t tot = v, pre = m;
    for (int o = 32; o; o >>= 1) {
      tot += __shfl_down(tot, o);
      pre += __shfl_down(pre, o);
    }
    if (lane == 0) { s_tot[wid] = tot; s_pre[wid] = pre; }
  }
  // bias finalize (wave 0)
  if (tid < 64) {
    float s = partial[(b << 6) | tid];
    for (int o = 32; o; o >>= 1) s += __shfl_down(s, o);
    if (tid == 0) s_bias = fmaxf(s * (1.0f / 262144.0f), 0.0f);
  }

  // pre-phase: classify this wave's 1024 pixels, pack cls 2b x 16 into a reg,
  // accumulate per-wave class counts (wave-uniform scalars)
  uint32_t clsreg = 0;
  uint32_t wc0 = 0, wc1 = 0, wc2 = 0, wc3 = 0;
#pragma unroll
  for (int k = 0; k < 16; ++k) {
    int i = (chunk << 12) + (k << 8) + tid;
    float f2 = pb[2 * HW + i];
    float f4 = pb[4 * HW + i];
    uint32_t cls = (f2 > 0.0f ? 1u : 0u) | (f4 > 0.0f ? 2u : 0u);
    clsreg |= cls << (2 * k);
    wc0 += (uint32_t)__popcll(__ballot(cls == 0u));
    wc1 += (uint32_t)__popcll(__ballot(cls == 1u));
    wc2 += (uint32_t)__popcll(__ballot(cls == 2u));
    wc3 += (uint32_t)__popcll(__ballot(cls == 3u));
  }
  if (lane == 0) {
    swcnt[wid][0] = wc0; swcnt[wid][1] = wc1;
    swcnt[wid][2] = wc2; swcnt[wid][3] = wc3;
  }
  __syncthreads();                       // the ONLY barrier

  // per-wave running slot offsets (registers, wave-uniform)
  uint32_t run[4];
#pragma unroll
  for (int c = 0; c < 4; ++c) {
    uint32_t cbase = 0;
    for (int cc = 0; cc < c; ++cc) cbase += s_tot[cc];
    uint32_t wb = 0;
    for (int w = 0; w < 4; ++w) if (w < wid) wb += swcnt[w][c];
    run[c] = cbase + s_pre[c] + wb;
  }
  float bias = s_bias;

  uint32_t* rbase = remarr + (size_t)b * HW;
  float4*   kbase = packed + (size_t)b * HW;
  float*    outc  = out + ACQ_N + (size_t)b * HW;

  for (int k = 0; k < 16; ++k) {
    int i = (chunk << 12) + (k << 8) + tid;
    float img = pb[i];
    float fw  = fmaxf(pb[2 * HW + i], 0.0f);
    float fa  = fmaxf(pb[3 * HW + i], 0.0f);
    float gw  = fmaxf(pb[4 * HW + i], 0.0f);
    float base = img + bias;
    // center = clip(base + fw*(1/(fa+1))^fa, 0, 1)  (coalesced write)
    float cpw = EXP2F(-fa * LOG2F(fa + 1.0f));
    outc[i] = fminf(fmaxf(fmaf(fw, cpw, base), 0.0f), 1.0f);

    uint32_t cls = (clsreg >> (2 * k)) & 3u;
    uint64_t ball[4];
#pragma unroll
    for (int c = 0; c < 4; ++c) ball[c] = __ballot(cls == (uint32_t)c);
    int rank = __popcll(ball[cls] & below);
    uint32_t slot = run[cls] + (uint32_t)rank;
#pragma unroll
    for (int c = 0; c < 4; ++c) run[c] += (uint32_t)__popcll(ball[c]);
    rbase[slot] = (uint32_t)i;
    kbase[slot] = make_float4(base, fw, fa, gw);
  }
}

// phase 3: coalesced packed reads, class-pure specialized loops.
// Block order REVERSED within each batch: heavy class-3 slots dispatch first,
// zero-work class-0 blocks backfill the drain (load-balance tail fix).
__global__ __launch_bounds__(256) void acquire_packed(
    const int* __restrict__ frames, const uint32_t* __restrict__ remarr,
    const float4* __restrict__ packed, float* __restrict__ out,
    uint32_t ku0, uint32_t ku1, uint32_t kn0, uint32_t kn1) {
  int b = blockIdx.x >> 10;
  int slot = ((1023 - (blockIdx.x & 1023)) << 8) | threadIdx.x;
  float4 op = packed[(size_t)b * HW + slot];   // coalesced 16 B
  uint32_t rem = remarr[(size_t)b * HW + slot];
  float base = op.x, fw = op.y, fa = op.z, gw = op.w;

  int nf = frames[b];                      // block-uniform
  bool fAny = __any(fw > 0.0f);            // wave-uniform
  bool gAny = __any(gw > 0.0f);
  uint32_t idx = ((uint32_t)b << 22) + rem;

  float res;
  if (fAny) {
    if (gAny) res = loop_fg(base, fw, fa, gw, idx, nf, ku0, ku1, kn0, kn1);
    else      res = loop_f(base, fw, fa, idx, nf, ku0, ku1);
  } else if (gAny) {
    res = loop_g(base, gw, idx, nf, kn0, kn1);
  } else {
    res = fminf(fmaxf(base, 0.0f), 1.0f);  // all frames identical
  }
  out[(size_t)b * HW + rem] = res;
}

// ================= plain tier (R5, proven fallback) =================
__global__ __launch_bounds__(256) void bias_partial(const float* __restrict__ inp,
                                                    float* __restrict__ partial) {
  int blk = blockIdx.x;
  int b = blk >> 6, chunk = blk & 63;
  const float4* src = (const float4*)(inp + ((size_t)b * 5 + 1) * HW
                                          + (size_t)chunk * 4096);
  int t = threadIdx.x;
  float s = 0.0f;
#pragma unroll
  for (int k = 0; k < 4; ++k) {
    float4 v = src[t + k * 256];
    s += (v.x + v.y) + (v.z + v.w);
  }
  for (int off = 32; off; off >>= 1) s += __shfl_down(s, off);
  __shared__ float ws4[4];
  if ((t & 63) == 0) ws4[t >> 6] = s;
  __syncthreads();
  if (t == 0) partial[blk] = ws4[0] + ws4[1] + ws4[2] + ws4[3];
}

__global__ __launch_bounds__(256) void acquire_plain(
    const float* __restrict__ inp, const int* __restrict__ frames,
    const float* __restrict__ partial, float* __restrict__ out,
    uint32_t ku0, uint32_t ku1, uint32_t kn0, uint32_t kn1) {
  int b = blockIdx.x >> 10;
  int rem = ((blockIdx.x & 1023) << 8) | threadIdx.x;
  __shared__ float s_bias;
  if (threadIdx.x < 64) {
    float s = partial[(b << 6) | threadIdx.x];
    for (int off = 32; off; off >>= 1) s += __shfl_down(s, off);
    if (threadIdx.x == 0) s_bias = fmaxf(s * (1.0f / 262144.0f), 0.0f);
  }
  const float* pb = inp + (size_t)b * 5 * HW;
  float img = pb[rem];
  float fw  = fmaxf(pb[2 * HW + rem], 0.0f);
  float fa  = fmaxf(pb[3 * HW + rem], 0.0f);
  float gw  = fmaxf(pb[4 * HW + rem], 0.0f);
  __syncthreads();
  float base = img + s_bias;
  int nf = frames[b];
  uint32_t idx = ((uint32_t)b << 22) + (uint32_t)rem;
  float res = loop_fg(base, fw, fa, gw, idx, nf, ku0, ku1, kn0, kn1);
  out[(size_t)b * HW + rem] = res;
  float cpw = EXP2F(-fa * LOG2F(fa + 1.0f));
  out[ACQ_N + (size_t)b * HW + rem] = fminf(fmaxf(fmaf(fw, cpw, base), 0.0f), 1.0f);
}

extern "C" void kernel_launch(void* const* d_in, const int* in_sizes, int n_in,
                              void* d_out, int out_size, void* d_ws, size_t ws_size,
                              hipStream_t stream) {
  const float* inp    = (const float*)d_in[0];
  const int*   frames = (const int*)d_in[1];
  float* out = (float*)d_out;

  // jax_threefry_partitionable=True: split(key(42)) foldlike:
  // ku = cipher((0,42),(0,0)), kn = cipher((0,42),(0,1))
  uint32_t ku0, ku1, kn0, kn1;
  tf2x32_host(0u, 42u, 0u, 0u, ku0, ku1);
  tf2x32_host(0u, 42u, 0u, 1u, kn0, kn1);

  float*    partial  = (float*)d_ws;                     // 512 f32
  uint32_t* blockcnt = (uint32_t*)((char*)d_ws + 2048);  // 512*4 u32
  const size_t need_full = 10240 + (size_t)8 * HW * 4 + (size_t)8 * HW * 16;

  if (ws_size >= need_full) {
    uint32_t* remarr = (uint32_t*)((char*)d_ws + 10240);
    float4*   packed = (float4*)((char*)d_ws + 10240 + (size_t)8 * HW * 4);
    count_cls<<<dim3(512), dim3(256), 0, stream>>>(inp, blockcnt, partial);
    scatter_pack<<<dim3(512), dim3(256), 0, stream>>>(inp, blockcnt, partial,
                                                      remarr, packed, out);
    acquire_packed<<<dim3(8192), dim3(256), 0, stream>>>(frames, remarr, packed,
                                                         out, ku0, ku1, kn0, kn1);
  } else {
    bias_partial<<<dim3(512), dim3(256), 0, stream>>>(inp, partial);
    acquire_plain<<<dim3(8192), dim3(256), 0, stream>>>(inp, frames, partial, out,
                                                        ku0, ku1, kn0, kn1);
  }
}